// Round 9
// baseline (228.068 us; speedup 1.0000x reference)
//
#include <hip/hip_runtime.h>
#include <hip/hip_fp16.h>

// Multi-Scale Deformable Attention:
//   cvt value fp32->fp16 + Wout^T fp16 (fused kernel, d_ws)
//   -> gather (fp16) with fused MFMA output-GEMM epilogue, acc kept in LDS
// BS=2, NQ=32768, C=128, NH=1, NL=2, NP=8, NV=40960
// level0 = 128x256 (start 0), level1 = 64x128 (start 32768)

#define QB 32  // queries per block (gather kernel)

struct __align__(8) h2x2 { __half2 a, b; };   // 4 fp16 channels (8 B)

typedef _Float16 f16x8 __attribute__((ext_vector_type(8)));
typedef _Float16 f16x4 __attribute__((ext_vector_type(4)));
typedef float    f32x4 __attribute__((ext_vector_type(4)));

// ---- value fp32 -> fp16 conversion (pure; fallback branch) ----
__global__ __launch_bounds__(256) void cvt_value_f16_kernel(
    const float4* __restrict__ in, h2x2* __restrict__ out, int n4)
{
    const int i = blockIdx.x * 256 + threadIdx.x;
    if (i < n4) {
        const float4 f = in[i];
        h2x2 h;
        h.a = __floats2half2_rn(f.x, f.y);
        h.b = __floats2half2_rn(f.z, f.w);
        out[i] = h;
    }
}

// ---- fused: value cvt (blocks 0..n4/256-1) + Wout transpose (last block) ----
__global__ __launch_bounds__(256) void cvt_value_f16_wt_kernel(
    const float4* __restrict__ in, h2x2* __restrict__ out, int n4,
    const float* __restrict__ Wout, _Float16* __restrict__ wTg)
{
    __shared__ float t[32 * 129];    // 16.5 KB
    const int tid = threadIdx.x;
    const int i = blockIdx.x * 256 + tid;
    if (i < n4) {
        const float4 f = in[i];
        h2x2 h;
        h.a = __floats2half2_rn(f.x, f.y);
        h.b = __floats2half2_rn(f.z, f.w);
        out[i] = h;
        return;
    }
    if (blockIdx.x != (unsigned)(n4 / 256)) return;   // only the extra block
    // transpose Wout (fp32 [k][n]) -> wTg (fp16 [n][k]) in 4 chunks of 32 rows
    #pragma unroll 1
    for (int c = 0; c < 4; ++c) {
        #pragma unroll
        for (int ii = 0; ii < 4; ++ii) {
            const int f  = tid + ii * 256;     // 0..1023 float4s
            const int r  = f >> 5;
            const int c4 = f & 31;
            const float4 v = ((const float4*)Wout)[(c * 32 + r) * 32 + c4];
            t[r * 129 + c4 * 4 + 0] = v.x;
            t[r * 129 + c4 * 4 + 1] = v.y;
            t[r * 129 + c4 * 4 + 2] = v.z;
            t[r * 129 + c4 * 4 + 3] = v.w;
        }
        __syncthreads();
        #pragma unroll
        for (int ii = 0; ii < 16; ++ii) {
            const int f = tid + ii * 256;      // 0..4095
            const int n = f >> 5;
            const int r = f & 31;
            wTg[n * 128 + c * 32 + r] = (_Float16)t[r * 129 + n];
        }
        __syncthreads();
    }
}

// ---------- shared prologue (R8, FROZEN: total LDS 16384 -> 8 blocks/CU) ----
// q_tile staged fp16 (8 KB) so coords (4 KB) fits inside the 16 KB smem_u.
// tab's k=1 entries overlap coords -> coord values buffered in regs + barrier
// before the table build. Thread mappings/GEMVs identical to R3/R7.
#define MSDA_PROLOGUE                                                          \
    _Float16* q_tile = (_Float16*)smem_u;                                      \
    float*    coords = (float*)(smem_u + 8192);                                \
    int4*     tab    = (int4*)smem_u;                                          \
    const int tid = threadIdx.x;                                               \
    const int r0  = blockIdx.x * QB;                                           \
    {                                                                          \
        const float4* src = (const float4*)query + (size_t)r0 * 32;            \
        f16x4* dst = (f16x4*)smem_u;                                           \
        _Pragma("unroll")                                                      \
        for (int i = 0; i < 4; ++i) {                                          \
            const float4 f = src[tid + i * 256];                               \
            f16x4 h;                                                           \
            h[0] = (_Float16)f.x; h[1] = (_Float16)f.y;                        \
            h[2] = (_Float16)f.z; h[3] = (_Float16)f.w;                        \
            dst[tid + i * 256] = h;                                            \
        }                                                                      \
    }                                                                          \
    __syncthreads();                                                           \
    {                                                                          \
        const int jo = tid & 31;                                               \
        const int qb = (tid >> 5) * 4;                                         \
        float s[4] = {0.f, 0.f, 0.f, 0.f};                                     \
        for (int c4 = 0; c4 < 32; ++c4) {                                      \
            const float w0 = Woff[(c4 * 4 + 0) * 32 + jo];                     \
            const float w1 = Woff[(c4 * 4 + 1) * 32 + jo];                     \
            const float w2 = Woff[(c4 * 4 + 2) * 32 + jo];                     \
            const float w3 = Woff[(c4 * 4 + 3) * 32 + jo];                     \
            _Pragma("unroll")                                                  \
            for (int k = 0; k < 4; ++k) {                                      \
                const f16x4 qh = *(const f16x4*)&q_tile[(qb + k) * 128 + c4 * 4]; \
                s[k] += (float)qh[0] * w0 + (float)qh[1] * w1                  \
                      + (float)qh[2] * w2 + (float)qh[3] * w3;                 \
            }                                                                  \
        }                                                                      \
        const int l = jo >> 4;                                                 \
        const int d = jo & 1;                                                  \
        const float scale = (d == 0) ? (l == 0 ? 256.f : 128.f)                \
                                     : (l == 0 ? 128.f : 64.f);                \
        const float bo = boff[jo];                                             \
        _Pragma("unroll")                                                      \
        for (int k = 0; k < 4; ++k) {                                          \
            const int row = r0 + qb + k;                                       \
            const float ql = qloc[row * 4 + l * 2 + d];                        \
            coords[(qb + k) * 32 + jo] = ql * scale + (s[k] + bo) - 0.5f;      \
        }                                                                      \
    }                                                                          \
    float wgt_[2];                                                             \
    {                                                                          \
        const int ja = tid & 15;                                               \
        const int qg = tid >> 4;             /* queries qg, qg+16 */           \
        float s[2] = {0.f, 0.f};                                               \
        for (int c4 = 0; c4 < 32; ++c4) {                                      \
            const float w0 = Wattn[(c4 * 4 + 0) * 16 + ja];                    \
            const float w1 = Wattn[(c4 * 4 + 1) * 16 + ja];                    \
            const float w2 = Wattn[(c4 * 4 + 2) * 16 + ja];                    \
            const float w3 = Wattn[(c4 * 4 + 3) * 16 + ja];                    \
            _Pragma("unroll")                                                  \
            for (int k = 0; k < 2; ++k) {                                      \
                const f16x4 qh = *(const f16x4*)&q_tile[(qg + 16 * k) * 128 + c4 * 4]; \
                s[k] += (float)qh[0] * w0 + (float)qh[1] * w1                  \
                      + (float)qh[2] * w2 + (float)qh[3] * w3;                 \
            }                                                                  \
        }                                                                      \
        const float ba = battn[ja];                                            \
        float lg0 = s[0] + ba, lg1 = s[1] + ba;                                \
        float m0 = lg0, m1 = lg1;                                              \
        _Pragma("unroll")                                                      \
        for (int s_ = 1; s_ < 16; s_ <<= 1) {                                  \
            m0 = fmaxf(m0, __shfl_xor(m0, s_, 64));                            \
            m1 = fmaxf(m1, __shfl_xor(m1, s_, 64));                            \
        }                                                                      \
        const float ex0 = __expf(lg0 - m0), ex1 = __expf(lg1 - m1);            \
        float sm0 = ex0, sm1 = ex1;                                            \
        _Pragma("unroll")                                                      \
        for (int s_ = 1; s_ < 16; s_ <<= 1) {                                  \
            sm0 += __shfl_xor(sm0, s_, 64);                                    \
            sm1 += __shfl_xor(sm1, s_, 64);                                    \
        }                                                                      \
        wgt_[0] = ex0 / sm0;                                                   \
        wgt_[1] = ex1 / sm1;                                                   \
    }                                                                          \
    __syncthreads();   /* q_tile reads done; coords visible */                 \
    float tx_[2], ty_[2];                                                      \
    _Pragma("unroll")                                                          \
    for (int k = 0; k < 2; ++k) {                                              \
        const int q = (tid >> 4) + 16 * k;                                     \
        const int p = tid & 15;                                                \
        tx_[k] = coords[q * 32 + p * 2 + 0];                                   \
        ty_[k] = coords[q * 32 + p * 2 + 1];                                   \
    }                                                                          \
    __syncthreads();   /* all coord reads done; tab may clobber coords */      \
    _Pragma("unroll")                                                          \
    for (int k = 0; k < 2; ++k) {                                              \
        const int q = (tid >> 4) + 16 * k;                                     \
        const int p = tid & 15;                                                \
        const int l = p >> 3;                                                  \
        const int H = l ? 64 : 128;                                            \
        const int W = l ? 128 : 256;                                           \
        const int S = l ? 32768 : 0;                                           \
        const float x   = tx_[k];                                              \
        const float y   = ty_[k];                                              \
        const float wgt = wgt_[k];                                             \
        const float xf = floorf(x), yf = floorf(y);                            \
        const float lx = x - xf, ly = y - yf;                                  \
        const int x0 = (int)xf, y0 = (int)yf;                                  \
        const int x1 = x0 + 1, y1 = y0 + 1;                                    \
        const float hx = 1.f - lx, hy = 1.f - ly;                              \
        float w00 = wgt * hx * hy;                                             \
        float w10 = wgt * lx * hy;                                             \
        float w01 = wgt * hx * ly;                                             \
        float w11 = wgt * lx * ly;                                             \
        if (x0 < 0 || x0 >= W) { w00 = 0.f; w01 = 0.f; }                       \
        if (x1 < 0 || x1 >= W) { w10 = 0.f; w11 = 0.f; }                       \
        if (y0 < 0 || y0 >= H) { w00 = 0.f; w10 = 0.f; }                       \
        if (y1 < 0 || y1 >= H) { w01 = 0.f; w11 = 0.f; }                       \
        const int cx0 = min(max(x0, 0), W - 1);                                \
        const int cx1 = min(max(x1, 0), W - 1);                                \
        const int cy0 = min(max(y0, 0), H - 1);                                \
        const int cy1 = min(max(y1, 0), H - 1);                                \
        int4 e0, e1;                                                           \
        e0.x = __float_as_int(w00); e0.y = __float_as_int(w01);                \
        e0.z = (S + cy0 * W + cx0) * 32; e0.w = (S + cy1 * W + cx0) * 32;      \
        e1.x = __float_as_int(w10); e1.y = __float_as_int(w11);                \
        e1.z = (S + cy0 * W + cx1) * 32; e1.w = (S + cy1 * W + cx1) * 32;      \
        const int e_ = q * 16 + p;                                             \
        tab[e_ * 2]     = e0;                                                  \
        tab[e_ * 2 + 1] = e1;                                                  \
    }                                                                          \
    __syncthreads();

// ---- gather fp16 + fused MFMA output-GEMM epilogue, acc in LDS ----
// R9 change (ONLY the main loop): the two 16-load batches per query are fused
// into ONE 32-load batch. 16 tab reads -> 32 value loads -> sched_barrier ->
// 128 FMAs. One memory-latency window per query instead of two; progressive
// vmcnt drain starts FMAs as the earliest loads land. Live data regs 32->64;
// weights are rematerializable from LDS tab (R8 showed the allocator does
// this). Everything else identical to R8 (224.0 us best).
__global__ __launch_bounds__(256, 4) void msda_gather_f16_kernel(
    const float* __restrict__ query,
    const h2x2*  __restrict__ value_h,
    const float* __restrict__ qloc,
    const float* __restrict__ Woff,
    const float* __restrict__ boff,
    const float* __restrict__ Wattn,
    const float* __restrict__ battn,
    const _Float16* __restrict__ wTg,
    const float* __restrict__ bout,
    float* __restrict__ acc_out)
{
    __shared__ __align__(16) char smem_u[QB * 128 * 4];   // 16 KB total: q/coords/tab/acc
    MSDA_PROLOGUE

    {
        const int wv   = tid >> 6;
        const int lane = tid & 63;
        const int half = lane >> 5;
        const int cl   = lane & 31;
        const h2x2* vb = value_h + (size_t)(blockIdx.x >> 10) * (40960 * 32);
        float4* sacc = (float4*)smem_u;

        #pragma unroll 1
        for (int i = 0; i < 8; ++i) {
            const int q = wv * 8 + i;
            float ax = 0.f, ay = 0.f, az = 0.f, aw4 = 0.f;

            float wa[16], wb[16];
            int   oa[16], ob[16];
            #pragma unroll
            for (int pi = 0; pi < 16; ++pi) {
                const int4 t = tab[((q * 16 + pi) << 1) + half];
                wa[pi] = __int_as_float(t.x);
                wb[pi] = __int_as_float(t.y);
                oa[pi] = t.z + cl;
                ob[pi] = t.w + cl;
            }
            h2x2 vA[16], vB[16];
            #pragma unroll
            for (int pi = 0; pi < 16; ++pi) {
                vA[pi] = vb[oa[pi]];
                vB[pi] = vb[ob[pi]];
            }
            __builtin_amdgcn_sched_barrier(0);   // all 32 loads in flight
            #pragma unroll
            for (int pi = 0; pi < 16; ++pi) {
                ax  += wa[pi] * __low2float(vA[pi].a);
                ay  += wa[pi] * __high2float(vA[pi].a);
                az  += wa[pi] * __low2float(vA[pi].b);
                aw4 += wa[pi] * __high2float(vA[pi].b);
                ax  += wb[pi] * __low2float(vB[pi].a);
                ay  += wb[pi] * __high2float(vB[pi].a);
                az  += wb[pi] * __low2float(vB[pi].b);
                aw4 += wb[pi] * __high2float(vB[pi].b);
            }
            ax  += __shfl_xor(ax, 32, 64);
            ay  += __shfl_xor(ay, 32, 64);
            az  += __shfl_xor(az, 32, 64);
            aw4 += __shfl_xor(aw4, 32, 64);
            if (half == 0)
                sacc[q * 32 + (cl ^ (q & 7))] = make_float4(ax, ay, az, aw4);
        }
    }

    // ---- fused output-GEMM epilogue (A from LDS) ----
    __syncthreads();   // all 32 swizzled acc rows visible across waves
    {
        const int wv   = tid >> 6;       // wave -> n-tiles wv*2, wv*2+1
        const int lane = tid & 63;
        const int quad = lane >> 4;
        const int lr   = lane & 15;
        const float4* sacc = (const float4*)smem_u;

        f16x8 afrag[2][4];
        #pragma unroll
        for (int mt = 0; mt < 2; ++mt) {
            const int r = mt * 16 + lr;
            #pragma unroll
            for (int k = 0; k < 4; ++k) {
                const int c0 = (k * 8 + quad * 2)     ^ (r & 7);
                const int c1 = (k * 8 + quad * 2 + 1) ^ (r & 7);
                const float4 v0 = sacc[r * 32 + c0];
                const float4 v1 = sacc[r * 32 + c1];
                f16x8 h;
                h[0] = (_Float16)v0.x; h[1] = (_Float16)v0.y;
                h[2] = (_Float16)v0.z; h[3] = (_Float16)v0.w;
                h[4] = (_Float16)v1.x; h[5] = (_Float16)v1.y;
                h[6] = (_Float16)v1.z; h[7] = (_Float16)v1.w;
                afrag[mt][k] = h;
            }
        }

        f32x4 acc2[2][2];
        #pragma unroll
        for (int mt = 0; mt < 2; ++mt)
            #pragma unroll
            for (int n2 = 0; n2 < 2; ++n2)
                acc2[mt][n2] = (f32x4){0.f, 0.f, 0.f, 0.f};

        #pragma unroll
        for (int n2 = 0; n2 < 2; ++n2) {
            const int nt = wv * 2 + n2;
            #pragma unroll
            for (int k = 0; k < 4; ++k) {
                const f16x8 b = *(const f16x8*)&wTg[(nt * 16 + lr) * 128 + k * 32 + quad * 8];
                acc2[0][n2] = __builtin_amdgcn_mfma_f32_16x16x32_f16(afrag[0][k], b, acc2[0][n2], 0, 0, 0);
                acc2[1][n2] = __builtin_amdgcn_mfma_f32_16x16x32_f16(afrag[1][k], b, acc2[1][n2], 0, 0, 0);
            }
        }

        #pragma unroll
        for (int n2 = 0; n2 < 2; ++n2) {
            const int nt = wv * 2 + n2;
            const float bb = bout[nt * 16 + lr];
            #pragma unroll
            for (int mt = 0; mt < 2; ++mt) {
                #pragma unroll
                for (int reg = 0; reg < 4; ++reg) {
                    const int row = mt * 16 + quad * 4 + reg;
                    acc_out[(size_t)(r0 + row) * 128 + nt * 16 + lr] = acc2[mt][n2][reg] + bb;
                }
            }
        }
    }
}

// ---- gather, fp32 fallback (ws too small; separate f32 GEMM afterwards) ----
// Kept in the R8 2-batch form (16B loads x32 in flight would spill).
__global__ __launch_bounds__(256, 4) void msda_gather_f32_kernel(
    const float* __restrict__ query,
    const float* __restrict__ value,
    const float* __restrict__ qloc,
    const float* __restrict__ Woff,
    const float* __restrict__ boff,
    const float* __restrict__ Wattn,
    const float* __restrict__ battn,
    float* __restrict__ acc_out)
{
    __shared__ __align__(16) char smem_u[QB * 128 * 4];   // 16 KB
    MSDA_PROLOGUE

    {
        const int wv   = tid >> 6;
        const int lane = tid & 63;
        const int half = lane >> 5;
        const int cl   = lane & 31;
        const float4* vb = (const float4*)value
                         + (size_t)(blockIdx.x >> 10) * (40960 * 32);
        float4* og = (float4*)acc_out;

        #pragma unroll 1
        for (int i = 0; i < 8; ++i) {
            const int q = wv * 8 + i;
            float ax = 0.f, ay = 0.f, az = 0.f, aw4 = 0.f;

            #pragma unroll 1
            for (int p0 = 0; p0 < 16; p0 += 8) {
                float wa[8], wb[8];
                int   oa[8], ob[8];
                #pragma unroll
                for (int pi = 0; pi < 8; ++pi) {
                    const int4 t = tab[((q * 16 + p0 + pi) << 1) + half];
                    wa[pi] = __int_as_float(t.x);
                    wb[pi] = __int_as_float(t.y);
                    oa[pi] = t.z + cl;
                    ob[pi] = t.w + cl;
                }
                float4 vA[8], vB[8];
                #pragma unroll
                for (int pi = 0; pi < 8; ++pi) {
                    vA[pi] = vb[oa[pi]];
                    vB[pi] = vb[ob[pi]];
                }
                __builtin_amdgcn_sched_barrier(0);   // keep all 16 loads in flight
                #pragma unroll
                for (int pi = 0; pi < 8; ++pi) {
                    ax  += wa[pi] * vA[pi].x + wb[pi] * vB[pi].x;
                    ay  += wa[pi] * vA[pi].y + wb[pi] * vB[pi].y;
                    az  += wa[pi] * vA[pi].z + wb[pi] * vB[pi].z;
                    aw4 += wa[pi] * vA[pi].w + wb[pi] * vB[pi].w;
                }
            }
            ax  += __shfl_xor(ax, 32, 64);
            ay  += __shfl_xor(ay, 32, 64);
            az  += __shfl_xor(az, 32, 64);
            aw4 += __shfl_xor(aw4, 32, 64);
            if (half == 0)
                og[(size_t)(r0 + q) * 32 + cl] = make_float4(ax, ay, az, aw4);
        }
    }
}

// ---- fp32 output GEMM fallback ----
#define GR 128
__global__ __launch_bounds__(256, 2) void msda_out_gemm_f32_kernel(
    const float* __restrict__ Wout,
    const float* __restrict__ bout,
    float* __restrict__ out)
{
    __shared__ __align__(16) float a_tile[GR * 68];
    __shared__ __align__(16) float w_tile[64 * 128];
    const int tid  = threadIdx.x;
    const int r0   = blockIdx.x * GR;
    const int trow = tid >> 4;
    const int tcol = tid & 15;

    float4 o[8][2];
    #pragma unroll
    for (int k = 0; k < 8; ++k) {
        o[k][0] = make_float4(0.f, 0.f, 0.f, 0.f);
        o[k][1] = make_float4(0.f, 0.f, 0.f, 0.f);
    }

    #pragma unroll 1
    for (int h = 0; h < 2; ++h) {
        {
            const float4* src = (const float4*)out;
            #pragma unroll
            for (int i = 0; i < 8; ++i) {
                const int t  = tid + i * 256;
                const int r  = t >> 4;
                const int c4 = t & 15;
                const float4 v = src[(size_t)(r0 + r) * 32 + h * 16 + c4];
                *(float4*)&a_tile[r * 68 + c4 * 4] = v;
            }
            const float4* ws = (const float4*)Wout + (size_t)h * 64 * 32;
            float4* wd = (float4*)w_tile;
            #pragma unroll
            for (int i = 0; i < 8; ++i)
                wd[tid + i * 256] = ws[tid + i * 256];
        }
        __syncthreads();

        #pragma unroll 1
        for (int c4 = 0; c4 < 16; ++c4) {
            float4 a4[8];
            #pragma unroll
            for (int k = 0; k < 8; ++k)
                a4[k] = *(const float4*)&a_tile[(trow + 16 * k) * 68 + c4 * 4];
            #pragma unroll
            for (int j = 0; j < 4; ++j) {
                const int ci = c4 * 4 + j;
                const float4 w0 = *(const float4*)&w_tile[ci * 128 + tcol * 4];
                const float4 w1 = *(const float4*)&w_tile[ci * 128 + 64 + tcol * 4];
                #pragma unroll
                for (int k = 0; k < 8; ++k) {
                    const float a = (j == 0) ? a4[k].x : (j == 1) ? a4[k].y
                                  : (j == 2) ? a4[k].z : a4[k].w;
                    o[k][0].x += a * w0.x; o[k][0].y += a * w0.y;
                    o[k][0].z += a * w0.z; o[k][0].w += a * w0.w;
                    o[k][1].x += a * w1.x; o[k][1].y += a * w1.y;
                    o[k][1].z += a * w1.z; o[k][1].w += a * w1.w;
                }
            }
        }
        __syncthreads();
    }

    const float4 b0 = ((const float4*)bout)[tcol];
    const float4 b1 = ((const float4*)bout)[16 + tcol];
    float4* og = (float4*)out;
    #pragma unroll
    for (int k = 0; k < 8; ++k) {
        const size_t row = (size_t)(r0 + trow + 16 * k);
        float4 v0 = o[k][0], v1 = o[k][1];
        v0.x += b0.x; v0.y += b0.y; v0.z += b0.z; v0.w += b0.w;
        v1.x += b1.x; v1.y += b1.y; v1.z += b1.z; v1.w += b1.w;
        og[row * 32 + tcol]      = v0;
        og[row * 32 + 16 + tcol] = v1;
    }
}

extern "C" void kernel_launch(void* const* d_in, const int* in_sizes, int n_in,
                              void* d_out, int out_size, void* d_ws, size_t ws_size,
                              hipStream_t stream) {
    const float* query = (const float*)d_in[0];
    const float* value = (const float*)d_in[1];
    const float* qloc  = (const float*)d_in[2];
    const float* Woff  = (const float*)d_in[5];
    const float* boff  = (const float*)d_in[6];
    const float* Wattn = (const float*)d_in[7];
    const float* battn = (const float*)d_in[8];
    const float* Wout  = (const float*)d_in[9];
    const float* bout  = (const float*)d_in[10];
    float* out = (float*)d_out;

    const int n_val = 2 * 40960 * 128;                 // 10,485,760 floats
    const size_t f16_bytes = (size_t)n_val * 2;        // 20,971,520 B
    const size_t wT_bytes  = 128 * 128 * 2;            // 32,768 B

    if (ws_size >= f16_bytes + wT_bytes) {
        h2x2* val16 = (h2x2*)d_ws;
        _Float16* wTg = (_Float16*)((char*)d_ws + f16_bytes);
        const int n4 = n_val / 4;                      // 2,621,440 (= 10240*256)
        hipLaunchKernelGGL(cvt_value_f16_wt_kernel, dim3(n4 / 256 + 1), dim3(256),
                           0, stream, (const float4*)value, val16, n4, Wout, wTg);
        hipLaunchKernelGGL(msda_gather_f16_kernel, dim3(65536 / QB), dim3(256),
                           0, stream,
                           query, (const h2x2*)val16, qloc, Woff, boff, Wattn, battn,
                           (const _Float16*)wTg, bout, out);
    } else {
        hipLaunchKernelGGL(msda_gather_f32_kernel, dim3(65536 / QB), dim3(256),
                           0, stream,
                           query, value, qloc, Woff, boff, Wattn, battn, out);
        hipLaunchKernelGGL(msda_out_gemm_f32_kernel, dim3(65536 / GR), dim3(256),
                           0, stream, Wout, bout, out);
    }
}

// Round 11
// 221.038 us; speedup vs baseline: 1.0318x; 1.0318x over previous
//
#include <hip/hip_runtime.h>
#include <hip/hip_fp16.h>

// Multi-Scale Deformable Attention — FINAL (R8; session best 224.0 us):
//   cvt value fp32->fp16 + Wout^T fp16 (fused kernel, d_ws)
//   -> gather (fp16) with fused MFMA output-GEMM epilogue, acc kept in LDS
// BS=2, NQ=32768, C=128, NH=1, NL=2, NP=8, NV=40960
// level0 = 128x256 (start 0), level1 = 64x128 (start 32768)
//
// Session ledger (why this exact shape):
//  - 16-load batch + sched_barrier(0) in the gather main loop: regalloc sweet
//    spot. Deeper (32, R9) or restructured (R1/R2/R4) variants all collapse
//    to <=56 VGPR and serialize -> +10..30% gather time.
//  - Total LDS = 16384 B exactly: 8 blocks/CU in one dispatch round. 20480 B
//    left 7 + a straggler round costing ~30-40 us (R3/R7).
//  - acc lives in tab's LDS slot (free exactly when acc is born); MFMA
//    epilogue reads it back swizzled -> no 64 MB acc round-trip (R6 vs R7).
//  - Gather is latency-bound at its practical floor: hbm 24%, VALU 51%,
//    occupancy 32 waves/CU, 16 loads/wave in flight (regalloc max).

#define QB 32  // queries per block (gather kernel)

struct __align__(8) h2x2 { __half2 a, b; };   // 4 fp16 channels (8 B)

typedef _Float16 f16x8 __attribute__((ext_vector_type(8)));
typedef _Float16 f16x4 __attribute__((ext_vector_type(4)));
typedef float    f32x4 __attribute__((ext_vector_type(4)));

// ---- value fp32 -> fp16 conversion (pure; fallback branch) ----
__global__ __launch_bounds__(256) void cvt_value_f16_kernel(
    const float4* __restrict__ in, h2x2* __restrict__ out, int n4)
{
    const int i = blockIdx.x * 256 + threadIdx.x;
    if (i < n4) {
        const float4 f = in[i];
        h2x2 h;
        h.a = __floats2half2_rn(f.x, f.y);
        h.b = __floats2half2_rn(f.z, f.w);
        out[i] = h;
    }
}

// ---- fused: value cvt (blocks 0..n4/256-1) + Wout transpose (last block) ----
__global__ __launch_bounds__(256) void cvt_value_f16_wt_kernel(
    const float4* __restrict__ in, h2x2* __restrict__ out, int n4,
    const float* __restrict__ Wout, _Float16* __restrict__ wTg)
{
    __shared__ float t[32 * 129];    // 16.5 KB
    const int tid = threadIdx.x;
    const int i = blockIdx.x * 256 + tid;
    if (i < n4) {
        const float4 f = in[i];
        h2x2 h;
        h.a = __floats2half2_rn(f.x, f.y);
        h.b = __floats2half2_rn(f.z, f.w);
        out[i] = h;
        return;
    }
    if (blockIdx.x != (unsigned)(n4 / 256)) return;   // only the extra block
    // transpose Wout (fp32 [k][n]) -> wTg (fp16 [n][k]) in 4 chunks of 32 rows
    #pragma unroll 1
    for (int c = 0; c < 4; ++c) {
        #pragma unroll
        for (int ii = 0; ii < 4; ++ii) {
            const int f  = tid + ii * 256;     // 0..1023 float4s
            const int r  = f >> 5;
            const int c4 = f & 31;
            const float4 v = ((const float4*)Wout)[(c * 32 + r) * 32 + c4];
            t[r * 129 + c4 * 4 + 0] = v.x;
            t[r * 129 + c4 * 4 + 1] = v.y;
            t[r * 129 + c4 * 4 + 2] = v.z;
            t[r * 129 + c4 * 4 + 3] = v.w;
        }
        __syncthreads();
        #pragma unroll
        for (int ii = 0; ii < 16; ++ii) {
            const int f = tid + ii * 256;      // 0..4095
            const int n = f >> 5;
            const int r = f & 31;
            wTg[n * 128 + c * 32 + r] = (_Float16)t[r * 129 + n];
        }
        __syncthreads();
    }
}

// ---------- shared prologue (R8, FROZEN: total LDS 16384 -> 8 blocks/CU) ----
// q_tile staged fp16 (8 KB) so coords (4 KB) fits inside the 16 KB smem_u.
// tab's k=1 entries overlap coords -> coord values buffered in regs + barrier
// before the table build. Thread mappings/GEMVs identical to R3/R7.
#define MSDA_PROLOGUE                                                          \
    _Float16* q_tile = (_Float16*)smem_u;                                      \
    float*    coords = (float*)(smem_u + 8192);                                \
    int4*     tab    = (int4*)smem_u;                                          \
    const int tid = threadIdx.x;                                               \
    const int r0  = blockIdx.x * QB;                                           \
    {                                                                          \
        const float4* src = (const float4*)query + (size_t)r0 * 32;            \
        f16x4* dst = (f16x4*)smem_u;                                           \
        _Pragma("unroll")                                                      \
        for (int i = 0; i < 4; ++i) {                                          \
            const float4 f = src[tid + i * 256];                               \
            f16x4 h;                                                           \
            h[0] = (_Float16)f.x; h[1] = (_Float16)f.y;                        \
            h[2] = (_Float16)f.z; h[3] = (_Float16)f.w;                        \
            dst[tid + i * 256] = h;                                            \
        }                                                                      \
    }                                                                          \
    __syncthreads();                                                           \
    {                                                                          \
        const int jo = tid & 31;                                               \
        const int qb = (tid >> 5) * 4;                                         \
        float s[4] = {0.f, 0.f, 0.f, 0.f};                                     \
        for (int c4 = 0; c4 < 32; ++c4) {                                      \
            const float w0 = Woff[(c4 * 4 + 0) * 32 + jo];                     \
            const float w1 = Woff[(c4 * 4 + 1) * 32 + jo];                     \
            const float w2 = Woff[(c4 * 4 + 2) * 32 + jo];                     \
            const float w3 = Woff[(c4 * 4 + 3) * 32 + jo];                     \
            _Pragma("unroll")                                                  \
            for (int k = 0; k < 4; ++k) {                                      \
                const f16x4 qh = *(const f16x4*)&q_tile[(qb + k) * 128 + c4 * 4]; \
                s[k] += (float)qh[0] * w0 + (float)qh[1] * w1                  \
                      + (float)qh[2] * w2 + (float)qh[3] * w3;                 \
            }                                                                  \
        }                                                                      \
        const int l = jo >> 4;                                                 \
        const int d = jo & 1;                                                  \
        const float scale = (d == 0) ? (l == 0 ? 256.f : 128.f)                \
                                     : (l == 0 ? 128.f : 64.f);                \
        const float bo = boff[jo];                                             \
        _Pragma("unroll")                                                      \
        for (int k = 0; k < 4; ++k) {                                          \
            const int row = r0 + qb + k;                                       \
            const float ql = qloc[row * 4 + l * 2 + d];                        \
            coords[(qb + k) * 32 + jo] = ql * scale + (s[k] + bo) - 0.5f;      \
        }                                                                      \
    }                                                                          \
    float wgt_[2];                                                             \
    {                                                                          \
        const int ja = tid & 15;                                               \
        const int qg = tid >> 4;             /* queries qg, qg+16 */           \
        float s[2] = {0.f, 0.f};                                               \
        for (int c4 = 0; c4 < 32; ++c4) {                                      \
            const float w0 = Wattn[(c4 * 4 + 0) * 16 + ja];                    \
            const float w1 = Wattn[(c4 * 4 + 1) * 16 + ja];                    \
            const float w2 = Wattn[(c4 * 4 + 2) * 16 + ja];                    \
            const float w3 = Wattn[(c4 * 4 + 3) * 16 + ja];                    \
            _Pragma("unroll")                                                  \
            for (int k = 0; k < 2; ++k) {                                      \
                const f16x4 qh = *(const f16x4*)&q_tile[(qg + 16 * k) * 128 + c4 * 4]; \
                s[k] += (float)qh[0] * w0 + (float)qh[1] * w1                  \
                      + (float)qh[2] * w2 + (float)qh[3] * w3;                 \
            }                                                                  \
        }                                                                      \
        const float ba = battn[ja];                                            \
        float lg0 = s[0] + ba, lg1 = s[1] + ba;                                \
        float m0 = lg0, m1 = lg1;                                              \
        _Pragma("unroll")                                                      \
        for (int s_ = 1; s_ < 16; s_ <<= 1) {                                  \
            m0 = fmaxf(m0, __shfl_xor(m0, s_, 64));                            \
            m1 = fmaxf(m1, __shfl_xor(m1, s_, 64));                            \
        }                                                                      \
        const float ex0 = __expf(lg0 - m0), ex1 = __expf(lg1 - m1);            \
        float sm0 = ex0, sm1 = ex1;                                            \
        _Pragma("unroll")                                                      \
        for (int s_ = 1; s_ < 16; s_ <<= 1) {                                  \
            sm0 += __shfl_xor(sm0, s_, 64);                                    \
            sm1 += __shfl_xor(sm1, s_, 64);                                    \
        }                                                                      \
        wgt_[0] = ex0 / sm0;                                                   \
        wgt_[1] = ex1 / sm1;                                                   \
    }                                                                          \
    __syncthreads();   /* q_tile reads done; coords visible */                 \
    float tx_[2], ty_[2];                                                      \
    _Pragma("unroll")                                                          \
    for (int k = 0; k < 2; ++k) {                                              \
        const int q = (tid >> 4) + 16 * k;                                     \
        const int p = tid & 15;                                                \
        tx_[k] = coords[q * 32 + p * 2 + 0];                                   \
        ty_[k] = coords[q * 32 + p * 2 + 1];                                   \
    }                                                                          \
    __syncthreads();   /* all coord reads done; tab may clobber coords */      \
    _Pragma("unroll")                                                          \
    for (int k = 0; k < 2; ++k) {                                              \
        const int q = (tid >> 4) + 16 * k;                                     \
        const int p = tid & 15;                                                \
        const int l = p >> 3;                                                  \
        const int H = l ? 64 : 128;                                            \
        const int W = l ? 128 : 256;                                           \
        const int S = l ? 32768 : 0;                                           \
        const float x   = tx_[k];                                              \
        const float y   = ty_[k];                                              \
        const float wgt = wgt_[k];                                             \
        const float xf = floorf(x), yf = floorf(y);                            \
        const float lx = x - xf, ly = y - yf;                                  \
        const int x0 = (int)xf, y0 = (int)yf;                                  \
        const int x1 = x0 + 1, y1 = y0 + 1;                                    \
        const float hx = 1.f - lx, hy = 1.f - ly;                              \
        float w00 = wgt * hx * hy;                                             \
        float w10 = wgt * lx * hy;                                             \
        float w01 = wgt * hx * ly;                                             \
        float w11 = wgt * lx * ly;                                             \
        if (x0 < 0 || x0 >= W) { w00 = 0.f; w01 = 0.f; }                       \
        if (x1 < 0 || x1 >= W) { w10 = 0.f; w11 = 0.f; }                       \
        if (y0 < 0 || y0 >= H) { w00 = 0.f; w10 = 0.f; }                       \
        if (y1 < 0 || y1 >= H) { w01 = 0.f; w11 = 0.f; }                       \
        const int cx0 = min(max(x0, 0), W - 1);                                \
        const int cx1 = min(max(x1, 0), W - 1);                                \
        const int cy0 = min(max(y0, 0), H - 1);                                \
        const int cy1 = min(max(y1, 0), H - 1);                                \
        int4 e0, e1;                                                           \
        e0.x = __float_as_int(w00); e0.y = __float_as_int(w01);                \
        e0.z = (S + cy0 * W + cx0) * 32; e0.w = (S + cy1 * W + cx0) * 32;      \
        e1.x = __float_as_int(w10); e1.y = __float_as_int(w11);                \
        e1.z = (S + cy0 * W + cx1) * 32; e1.w = (S + cy1 * W + cx1) * 32;      \
        const int e_ = q * 16 + p;                                             \
        tab[e_ * 2]     = e0;                                                  \
        tab[e_ * 2 + 1] = e1;                                                  \
    }                                                                          \
    __syncthreads();

// ---- gather fp16 + fused MFMA output-GEMM epilogue, acc in LDS ----
// Main loop: two 16-load batches per query, each pinned by sched_barrier(0)
// (R9 proved 32-deep is unreachable: allocator caps ~56 VGPR and serializes).
// Per-query acc written into tab's LDS row-q region (512 B; wave wv reads tab
// row-q only BEFORE producing acc[q]; no other wave touches it). XOR swizzle
// (chunk ^= row&7) makes the epilogue's 16-rows-same-column A-read
// bank-conflict-free. Epilogue: barrier -> A from LDS (cvt fp16) -> B from
// L2-resident wTg -> 16 MFMAs -> single final global write (+bias).
__global__ __launch_bounds__(256, 4) void msda_gather_f16_kernel(
    const float* __restrict__ query,
    const h2x2*  __restrict__ value_h,
    const float* __restrict__ qloc,
    const float* __restrict__ Woff,
    const float* __restrict__ boff,
    const float* __restrict__ Wattn,
    const float* __restrict__ battn,
    const _Float16* __restrict__ wTg,
    const float* __restrict__ bout,
    float* __restrict__ acc_out)
{
    __shared__ __align__(16) char smem_u[QB * 128 * 4];   // 16 KB total: q/coords/tab/acc
    MSDA_PROLOGUE

    {
        const int wv   = tid >> 6;
        const int lane = tid & 63;
        const int half = lane >> 5;
        const int cl   = lane & 31;
        const h2x2* vb = value_h + (size_t)(blockIdx.x >> 10) * (40960 * 32);
        float4* sacc = (float4*)smem_u;

        #pragma unroll 1
        for (int i = 0; i < 8; ++i) {
            const int q = wv * 8 + i;
            float ax = 0.f, ay = 0.f, az = 0.f, aw4 = 0.f;

            #pragma unroll 1
            for (int p0 = 0; p0 < 16; p0 += 8) {
                float wa[8], wb[8];
                int   oa[8], ob[8];
                #pragma unroll
                for (int pi = 0; pi < 8; ++pi) {
                    const int4 t = tab[((q * 16 + p0 + pi) << 1) + half];
                    wa[pi] = __int_as_float(t.x);
                    wb[pi] = __int_as_float(t.y);
                    oa[pi] = t.z + cl;
                    ob[pi] = t.w + cl;
                }
                h2x2 vA[8], vB[8];
                #pragma unroll
                for (int pi = 0; pi < 8; ++pi) {
                    vA[pi] = vb[oa[pi]];
                    vB[pi] = vb[ob[pi]];
                }
                __builtin_amdgcn_sched_barrier(0);   // keep all 16 loads in flight
                #pragma unroll
                for (int pi = 0; pi < 8; ++pi) {
                    ax  += wa[pi] * __low2float(vA[pi].a);
                    ay  += wa[pi] * __high2float(vA[pi].a);
                    az  += wa[pi] * __low2float(vA[pi].b);
                    aw4 += wa[pi] * __high2float(vA[pi].b);
                    ax  += wb[pi] * __low2float(vB[pi].a);
                    ay  += wb[pi] * __high2float(vB[pi].a);
                    az  += wb[pi] * __low2float(vB[pi].b);
                    aw4 += wb[pi] * __high2float(vB[pi].b);
                }
            }
            ax  += __shfl_xor(ax, 32, 64);
            ay  += __shfl_xor(ay, 32, 64);
            az  += __shfl_xor(az, 32, 64);
            aw4 += __shfl_xor(aw4, 32, 64);
            if (half == 0)
                sacc[q * 32 + (cl ^ (q & 7))] = make_float4(ax, ay, az, aw4);
        }
    }

    // ---- fused output-GEMM epilogue (A from LDS) ----
    __syncthreads();   // all 32 swizzled acc rows visible across waves
    {
        const int wv   = tid >> 6;       // wave -> n-tiles wv*2, wv*2+1
        const int lane = tid & 63;
        const int quad = lane >> 4;
        const int lr   = lane & 15;
        const float4* sacc = (const float4*)smem_u;

        f16x8 afrag[2][4];
        #pragma unroll
        for (int mt = 0; mt < 2; ++mt) {
            const int r = mt * 16 + lr;
            #pragma unroll
            for (int k = 0; k < 4; ++k) {
                const int c0 = (k * 8 + quad * 2)     ^ (r & 7);
                const int c1 = (k * 8 + quad * 2 + 1) ^ (r & 7);
                const float4 v0 = sacc[r * 32 + c0];
                const float4 v1 = sacc[r * 32 + c1];
                f16x8 h;
                h[0] = (_Float16)v0.x; h[1] = (_Float16)v0.y;
                h[2] = (_Float16)v0.z; h[3] = (_Float16)v0.w;
                h[4] = (_Float16)v1.x; h[5] = (_Float16)v1.y;
                h[6] = (_Float16)v1.z; h[7] = (_Float16)v1.w;
                afrag[mt][k] = h;
            }
        }

        f32x4 acc2[2][2];
        #pragma unroll
        for (int mt = 0; mt < 2; ++mt)
            #pragma unroll
            for (int n2 = 0; n2 < 2; ++n2)
                acc2[mt][n2] = (f32x4){0.f, 0.f, 0.f, 0.f};

        #pragma unroll
        for (int n2 = 0; n2 < 2; ++n2) {
            const int nt = wv * 2 + n2;
            #pragma unroll
            for (int k = 0; k < 4; ++k) {
                const f16x8 b = *(const f16x8*)&wTg[(nt * 16 + lr) * 128 + k * 32 + quad * 8];
                acc2[0][n2] = __builtin_amdgcn_mfma_f32_16x16x32_f16(afrag[0][k], b, acc2[0][n2], 0, 0, 0);
                acc2[1][n2] = __builtin_amdgcn_mfma_f32_16x16x32_f16(afrag[1][k], b, acc2[1][n2], 0, 0, 0);
            }
        }

        #pragma unroll
        for (int n2 = 0; n2 < 2; ++n2) {
            const int nt = wv * 2 + n2;
            const float bb = bout[nt * 16 + lr];
            #pragma unroll
            for (int mt = 0; mt < 2; ++mt) {
                #pragma unroll
                for (int reg = 0; reg < 4; ++reg) {
                    const int row = mt * 16 + quad * 4 + reg;
                    acc_out[(size_t)(r0 + row) * 128 + nt * 16 + lr] = acc2[mt][n2][reg] + bb;
                }
            }
        }
    }
}

// ---- gather, fp32 fallback (ws too small; separate f32 GEMM afterwards) ----
__global__ __launch_bounds__(256, 4) void msda_gather_f32_kernel(
    const float* __restrict__ query,
    const float* __restrict__ value,
    const float* __restrict__ qloc,
    const float* __restrict__ Woff,
    const float* __restrict__ boff,
    const float* __restrict__ Wattn,
    const float* __restrict__ battn,
    float* __restrict__ acc_out)
{
    __shared__ __align__(16) char smem_u[QB * 128 * 4];   // 16 KB
    MSDA_PROLOGUE

    {
        const int wv   = tid >> 6;
        const int lane = tid & 63;
        const int half = lane >> 5;
        const int cl   = lane & 31;
        const float4* vb = (const float4*)value
                         + (size_t)(blockIdx.x >> 10) * (40960 * 32);
        float4* og = (float4*)acc_out;

        #pragma unroll 1
        for (int i = 0; i < 8; ++i) {
            const int q = wv * 8 + i;
            float ax = 0.f, ay = 0.f, az = 0.f, aw4 = 0.f;

            #pragma unroll 1
            for (int p0 = 0; p0 < 16; p0 += 8) {
                float wa[8], wb[8];
                int   oa[8], ob[8];
                #pragma unroll
                for (int pi = 0; pi < 8; ++pi) {
                    const int4 t = tab[((q * 16 + p0 + pi) << 1) + half];
                    wa[pi] = __int_as_float(t.x);
                    wb[pi] = __int_as_float(t.y);
                    oa[pi] = t.z + cl;
                    ob[pi] = t.w + cl;
                }
                float4 vA[8], vB[8];
                #pragma unroll
                for (int pi = 0; pi < 8; ++pi) {
                    vA[pi] = vb[oa[pi]];
                    vB[pi] = vb[ob[pi]];
                }
                __builtin_amdgcn_sched_barrier(0);   // keep all 16 loads in flight
                #pragma unroll
                for (int pi = 0; pi < 8; ++pi) {
                    ax  += wa[pi] * vA[pi].x + wb[pi] * vB[pi].x;
                    ay  += wa[pi] * vA[pi].y + wb[pi] * vB[pi].y;
                    az  += wa[pi] * vA[pi].z + wb[pi] * vB[pi].z;
                    aw4 += wa[pi] * vA[pi].w + wb[pi] * vB[pi].w;
                }
            }
            ax  += __shfl_xor(ax, 32, 64);
            ay  += __shfl_xor(ay, 32, 64);
            az  += __shfl_xor(az, 32, 64);
            aw4 += __shfl_xor(aw4, 32, 64);
            if (half == 0)
                og[(size_t)(r0 + q) * 32 + cl] = make_float4(ax, ay, az, aw4);
        }
    }
}

// ---- fp32 output GEMM fallback ----
#define GR 128
__global__ __launch_bounds__(256, 2) void msda_out_gemm_f32_kernel(
    const float* __restrict__ Wout,
    const float* __restrict__ bout,
    float* __restrict__ out)
{
    __shared__ __align__(16) float a_tile[GR * 68];
    __shared__ __align__(16) float w_tile[64 * 128];
    const int tid  = threadIdx.x;
    const int r0   = blockIdx.x * GR;
    const int trow = tid >> 4;
    const int tcol = tid & 15;

    float4 o[8][2];
    #pragma unroll
    for (int k = 0; k < 8; ++k) {
        o[k][0] = make_float4(0.f, 0.f, 0.f, 0.f);
        o[k][1] = make_float4(0.f, 0.f, 0.f, 0.f);
    }

    #pragma unroll 1
    for (int h = 0; h < 2; ++h) {
        {
            const float4* src = (const float4*)out;
            #pragma unroll
            for (int i = 0; i < 8; ++i) {
                const int t  = tid + i * 256;
                const int r  = t >> 4;
                const int c4 = t & 15;
                const float4 v = src[(size_t)(r0 + r) * 32 + h * 16 + c4];
                *(float4*)&a_tile[r * 68 + c4 * 4] = v;
            }
            const float4* ws = (const float4*)Wout + (size_t)h * 64 * 32;
            float4* wd = (float4*)w_tile;
            #pragma unroll
            for (int i = 0; i < 8; ++i)
                wd[tid + i * 256] = ws[tid + i * 256];
        }
        __syncthreads();

        #pragma unroll 1
        for (int c4 = 0; c4 < 16; ++c4) {
            float4 a4[8];
            #pragma unroll
            for (int k = 0; k < 8; ++k)
                a4[k] = *(const float4*)&a_tile[(trow + 16 * k) * 68 + c4 * 4];
            #pragma unroll
            for (int j = 0; j < 4; ++j) {
                const int ci = c4 * 4 + j;
                const float4 w0 = *(const float4*)&w_tile[ci * 128 + tcol * 4];
                const float4 w1 = *(const float4*)&w_tile[ci * 128 + 64 + tcol * 4];
                #pragma unroll
                for (int k = 0; k < 8; ++k) {
                    const float a = (j == 0) ? a4[k].x : (j == 1) ? a4[k].y
                                  : (j == 2) ? a4[k].z : a4[k].w;
                    o[k][0].x += a * w0.x; o[k][0].y += a * w0.y;
                    o[k][0].z += a * w0.z; o[k][0].w += a * w0.w;
                    o[k][1].x += a * w1.x; o[k][1].y += a * w1.y;
                    o[k][1].z += a * w1.z; o[k][1].w += a * w1.w;
                }
            }
        }
        __syncthreads();
    }

    const float4 b0 = ((const float4*)bout)[tcol];
    const float4 b1 = ((const float4*)bout)[16 + tcol];
    float4* og = (float4*)out;
    #pragma unroll
    for (int k = 0; k < 8; ++k) {
        const size_t row = (size_t)(r0 + trow + 16 * k);
        float4 v0 = o[k][0], v1 = o[k][1];
        v0.x += b0.x; v0.y += b0.y; v0.z += b0.z; v0.w += b0.w;
        v1.x += b1.x; v1.y += b1.y; v1.z += b1.z; v1.w += b1.w;
        og[row * 32 + tcol]      = v0;
        og[row * 32 + 16 + tcol] = v1;
    }
}

extern "C" void kernel_launch(void* const* d_in, const int* in_sizes, int n_in,
                              void* d_out, int out_size, void* d_ws, size_t ws_size,
                              hipStream_t stream) {
    const float* query = (const float*)d_in[0];
    const float* value = (const float*)d_in[1];
    const float* qloc  = (const float*)d_in[2];
    const float* Woff  = (const float*)d_in[5];
    const float* boff  = (const float*)d_in[6];
    const float* Wattn = (const float*)d_in[7];
    const float* battn = (const float*)d_in[8];
    const float* Wout  = (const float*)d_in[9];
    const float* bout  = (const float*)d_in[10];
    float* out = (float*)d_out;

    const int n_val = 2 * 40960 * 128;                 // 10,485,760 floats
    const size_t f16_bytes = (size_t)n_val * 2;        // 20,971,520 B
    const size_t wT_bytes  = 128 * 128 * 2;            // 32,768 B

    if (ws_size >= f16_bytes + wT_bytes) {
        h2x2* val16 = (h2x2*)d_ws;
        _Float16* wTg = (_Float16*)((char*)d_ws + f16_bytes);
        const int n4 = n_val / 4;                      // 2,621,440 (= 10240*256)
        hipLaunchKernelGGL(cvt_value_f16_wt_kernel, dim3(n4 / 256 + 1), dim3(256),
                           0, stream, (const float4*)value, val16, n4, Wout, wTg);
        hipLaunchKernelGGL(msda_gather_f16_kernel, dim3(65536 / QB), dim3(256),
                           0, stream,
                           query, (const h2x2*)val16, qloc, Woff, boff, Wattn, battn,
                           (const _Float16*)wTg, bout, out);
    } else {
        hipLaunchKernelGGL(msda_gather_f32_kernel, dim3(65536 / QB), dim3(256),
                           0, stream,
                           query, value, qloc, Woff, boff, Wattn, battn, out);
        hipLaunchKernelGGL(msda_out_gemm_f32_kernel, dim3(65536 / GR), dim3(256),
                           0, stream, Wout, bout, out);
    }
}